// Round 2
// baseline (361.836 us; speedup 1.0000x reference)
//
#include <hip/hip_runtime.h>
#include <hip/hip_bf16.h>
#include <string.h>

// Batched GEMM: out[b,o,f] = sum_i W[b,o,i] * x[b,i,f]
// B=32, M(O)=1024, K(I)=1024, N(F)=2048, fp32 in/out, bf16 MFMA compute.

typedef float f32x4 __attribute__((ext_vector_type(4)));
typedef short bf16x8 __attribute__((ext_vector_type(8)));

#define BATCH 32
#define MDIM 1024
#define KDIM 1024
#define NDIM 2048
#define BM 128
#define BN 128
#define BK 32

__device__ __forceinline__ unsigned int cvt2(float a, float b) {
    float2 t; t.x = a; t.y = b;
    __hip_bfloat162 h = __float22bfloat162_rn(t);   // v_cvt_pk_bf16_f32 (RTNE)
    unsigned int r;
    memcpy(&r, &h, 4);
    return r;
}

__global__ __launch_bounds__(256) void bgemm_bf16_kernel(
    const float* __restrict__ x, const float* __restrict__ w,
    float* __restrict__ out)
{
    // LDS tiles, bf16 stored as ushort. Layout: [row][k ^ ((row&3)<<3)]
    // XOR swizzle keeps ds_read_b128 fragment reads bank-balanced.
    __shared__ unsigned short Ab[BM * BK];  // A = W tile, [m][k]
    __shared__ unsigned short Bb[BN * BK];  // B = x tile transposed, [n][k]

    const int tid = threadIdx.x;
    const int b   = blockIdx.z;
    const int m0  = blockIdx.y * BM;
    const int n0  = blockIdx.x * BN;

    const float* Ag = w + (size_t)b * MDIM * KDIM + (size_t)m0 * KDIM;
    const float* Bg = x + (size_t)b * KDIM * NDIM + n0;
    float*       Cg = out + (size_t)b * MDIM * NDIM + (size_t)m0 * NDIM + n0;

    // A staging: thread -> (row a_m + 32*i, float4 col a_k4), k-contiguous loads
    const int a_k4 = tid & 7;    // float4 index within a 32-wide k row
    const int a_m  = tid >> 3;   // 0..31
    // B staging: thread -> 4 consecutive k rows (b_kg*4+j) at n = b_n4*4..+3
    const int b_n4 = tid & 31;
    const int b_kg = tid >> 5;   // 0..7

    const int lane = tid & 63;
    const int wid  = tid >> 6;
    const int wm   = (wid >> 1) * 64;  // wave row origin in tile
    const int wn   = (wid & 1)  * 64;  // wave col origin in tile
    const int l15  = lane & 15;
    const int kg8  = (lane >> 4) * 8;  // k offset of this lane's fragment slice

    f32x4 acc[4][4];
    #pragma unroll
    for (int i = 0; i < 4; ++i)
        #pragma unroll
        for (int j = 0; j < 4; ++j)
            acc[i][j] = f32x4{0.f, 0.f, 0.f, 0.f};

    for (int kt = 0; kt < KDIM; kt += BK) {
        // ---- global -> regs (coalesced dwordx4) ----
        f32x4 av[4], bv[4];
        #pragma unroll
        for (int i = 0; i < 4; ++i)
            av[i] = *reinterpret_cast<const f32x4*>(
                Ag + (size_t)(a_m + 32 * i) * KDIM + kt + a_k4 * 4);
        #pragma unroll
        for (int j = 0; j < 4; ++j)
            bv[j] = *reinterpret_cast<const f32x4*>(
                Bg + (size_t)(kt + b_kg * 4 + j) * NDIM + b_n4 * 4);

        __syncthreads();  // previous iteration's compute done before overwrite

        // ---- convert fp32->bf16, write LDS ----
        // A: k-contiguous pack, one ds_write_b64 per row slice
        #pragma unroll
        for (int i = 0; i < 4; ++i) {
            int m = a_m + 32 * i;
            unsigned long long p =
                (unsigned long long)cvt2(av[i][0], av[i][1]) |
                ((unsigned long long)cvt2(av[i][2], av[i][3]) << 32);
            int idx = m * BK + ((a_k4 * 4) ^ ((m & 3) << 3));
            *reinterpret_cast<unsigned long long*>(&Ab[idx]) = p;
        }
        // B: transpose during write — pack 4 k-values for one n, staggered di
        // to spread bank usage.
        #pragma unroll
        for (int di = 0; di < 4; ++di) {
            int c = (di + b_n4) & 3;
            int n = b_n4 * 4 + c;
            unsigned long long p =
                (unsigned long long)cvt2(bv[0][c], bv[1][c]) |
                ((unsigned long long)cvt2(bv[2][c], bv[3][c]) << 32);
            int idx = n * BK + ((b_kg * 4) ^ (c << 3));
            *reinterpret_cast<unsigned long long*>(&Bb[idx]) = p;
        }
        __syncthreads();

        // ---- LDS -> fragments -> MFMA ----
        bf16x8 af[4], bfr[4];
        #pragma unroll
        for (int mi = 0; mi < 4; ++mi) {
            int m = wm + mi * 16 + l15;
            af[mi] = *reinterpret_cast<const bf16x8*>(
                &Ab[m * BK + (kg8 ^ ((m & 3) << 3))]);
        }
        #pragma unroll
        for (int ni = 0; ni < 4; ++ni) {
            int n = wn + ni * 16 + l15;
            bfr[ni] = *reinterpret_cast<const bf16x8*>(
                &Bb[n * BK + (kg8 ^ ((n & 3) << 3))]);
        }
        #pragma unroll
        for (int mi = 0; mi < 4; ++mi)
            #pragma unroll
            for (int ni = 0; ni < 4; ++ni)
                acc[mi][ni] = __builtin_amdgcn_mfma_f32_16x16x32_bf16(
                    af[mi], bfr[ni], acc[mi][ni], 0, 0, 0);
    }

    // ---- epilogue: D layout col=lane&15, row=(lane>>4)*4+reg ----
    const int rbase = (lane >> 4) * 4;
    #pragma unroll
    for (int mi = 0; mi < 4; ++mi) {
        #pragma unroll
        for (int ni = 0; ni < 4; ++ni) {
            int n  = wn + ni * 16 + l15;
            int mb = wm + mi * 16 + rbase;
            #pragma unroll
            for (int r = 0; r < 4; ++r)
                Cg[(size_t)(mb + r) * NDIM + n] = acc[mi][ni][r];
        }
    }
}

extern "C" void kernel_launch(void* const* d_in, const int* in_sizes, int n_in,
                              void* d_out, int out_size, void* d_ws, size_t ws_size,
                              hipStream_t stream) {
    const float* x = (const float*)d_in[0];   // [32][1024][2048]
    const float* w = (const float*)d_in[1];   // [32][1024][1024]
    float* out = (float*)d_out;               // [32][1024][2048]
    dim3 grid(NDIM / BN, MDIM / BM, BATCH);
    bgemm_bf16_kernel<<<grid, dim3(256), 0, stream>>>(x, w, out);
}